// Round 10
// baseline (338.186 us; speedup 1.0000x reference)
//
#include <hip/hip_runtime.h>
#include <cstdint>

// Problem constants
#define NROWS   131072
#define NUNITS  256
#define KTOT    512          // INPUT_DIM + UNITS
#define BM      256          // rows per block
#define THREADS 512

typedef float f32x4  __attribute__((ext_vector_type(4)));
typedef short bf16x8 __attribute__((ext_vector_type(8)));

__device__ __forceinline__ short f2bf(float x) {
    unsigned u = __float_as_uint(x);
    u += 0x7FFFu + ((u >> 16) & 1u);   // round-to-nearest-even
    return (short)(u >> 16);
}

// Fused prepass: blocks [0,32768) convert x|h -> Aws bf16 [row][512];
// blocks [32768,34816) convert W fp32 [512][1024] -> Wws [16][1024][32] bf16
// (per-K32-step, column-major, 32 contiguous k per col = B-frag order).
__global__ void convert_kernel(const float* __restrict__ x, const float* __restrict__ h,
                               const float* __restrict__ W,
                               short* __restrict__ Aws, short* __restrict__ Wws) {
    int b = blockIdx.x;
    if (b < 32768) {
        int i = b * 256 + threadIdx.x;       // 0 .. 8388607
        int row = i >> 6;
        int c   = (i & 63) * 4;
        float4 xv = *(const float4*)(x + (size_t)row * 256 + c);
        float4 hv = *(const float4*)(h + (size_t)row * 256 + c);
        short xs[4] = {f2bf(xv.x), f2bf(xv.y), f2bf(xv.z), f2bf(xv.w)};
        short hs[4] = {f2bf(hv.x), f2bf(hv.y), f2bf(hv.z), f2bf(hv.w)};
        *(uint2*)(Aws + (size_t)row * 512 + c)       = *(uint2*)xs;
        *(uint2*)(Aws + (size_t)row * 512 + 256 + c) = *(uint2*)hs;
    } else {
        int i = (b - 32768) * 256 + threadIdx.x;   // 0 .. 524287
        int k = i >> 10;
        int c = i & 1023;
        Wws[((size_t)(k >> 5) << 15) + ((size_t)c << 5) + (k & 31)] = f2bf(W[i]);
    }
}

// Main: grid 2048 = 512 row-tiles x 4 u-tiles (XCD-swizzled).
// Block: 256 rows x 64 u x 4 gates. 8 waves = 2 row-halves x 4 col-quarters;
// wave tile 128x64cols, acc[8][4] (all 4 gates lane-local -> fused epilogue).
// K-loop: 16 phases of BK=32. Per phase/thread: 4 global_load_lds(16B)
// (A 16KB + B 16KB per block); per phase/wave: 12 ds_read_b128 + 32 MFMA.
// FOUR LDS buffers (4 x 32KB = 128 KiB), DMA issued 3 phases ahead, counted
// s_waitcnt vmcnt(8) per phase -- never a mid-loop drain (T4); one raw
// s_barrier per phase; setprio around the MFMA cluster (T5).
// Layouts are R7's measured-conflict-free schemes (64B stride, granule XOR
// (row>>1)&3, pre-swizzled on the DMA SOURCE, LDS dest linear -- rule #21).
__global__ void __launch_bounds__(THREADS, 2)
lstm_main_kernel(const float* __restrict__ c_prev, const float* __restrict__ bias,
                 const float* __restrict__ pi, const float* __restrict__ pf,
                 const float* __restrict__ po, const short* __restrict__ Aws,
                 const short* __restrict__ Wws, float* __restrict__ out) {
    __shared__ short lds[4][16384];   // per buf: A [0,8192), B [8192,16384)

    // XCD-aware bijective swizzle (2048 % 8 == 0): the 4 u-tiles of one
    // row-panel land adjacent on one XCD -> A panel L2-reused.
    const int bid = blockIdx.x;
    const int swz = (bid & 7) * 256 + (bid >> 3);
    const int ut  = swz & 3;
    const int rt  = swz >> 2;
    const int row0 = rt * BM;

    const int t    = threadIdx.x;
    const int lane = t & 63;
    const int w    = t >> 6;
    const int lr   = lane & 15;
    const int hi   = lane >> 4;          // k-granule 0..3
    const int rh   = w >> 2;             // row half 0..1 (128 rows each)
    const int q    = w & 3;              // col quarter 0..3 (16 u each)

    // ---- DMA source bases (granule-swizzled with (row>>1)&3) ----
    // A: granule G=t covers row t>>2, LDS slot t&3; chunk1 (G=t+512) = +128 rows
    const int arow = t >> 2, aslot = t & 3;
    const short* srcA0 = Aws + (size_t)(row0 + arow) * 512
                             + ((aslot ^ ((arow >> 1) & 3)) * 8);
    // B: granule G=t covers LDS col t>>2 (gate*64+u), slot t&3; chunk1 = +2 gates
    const int bcol = t >> 2, bslot = t & 3;
    const int gate0 = bcol >> 6, u64c = bcol & 63;
    const short* srcB0 = Wws + (size_t)(gate0 * 256 + ut * 64 + u64c) * 32
                             + ((bslot ^ ((bcol >> 1) & 3)) * 8);

    // ---- fragment read offsets (shorts): swizzle matches write side ----
    const int sw   = (hi ^ ((lr >> 1) & 3)) * 8;
    const int aoff = (rh * 128 + lr) * 32 + sw;          // + m*512
    const int boff = 8192 + (q * 16 + lr) * 32 + sw;     // + g*2048

    f32x4 acc[8][4];
    #pragma unroll
    for (int m = 0; m < 8; ++m)
        #pragma unroll
        for (int g = 0; g < 4; ++g)
            acc[m][g] = (f32x4){0.f, 0.f, 0.f, 0.f};

    auto dma = [&](int ks, int buf) {
        short* dst = &lds[buf][0];
        const short* a0 = srcA0 + ks * 32;
        const short* b0 = srcB0 + (size_t)ks * 32768;
        __builtin_amdgcn_global_load_lds(
            (const __attribute__((address_space(1))) uint32_t*)(const void*)a0,
            (__attribute__((address_space(3))) uint32_t*)(void*)(dst + t * 8), 16, 0, 0);
        __builtin_amdgcn_global_load_lds(
            (const __attribute__((address_space(1))) uint32_t*)(const void*)(a0 + 65536),
            (__attribute__((address_space(3))) uint32_t*)(void*)(dst + 4096 + t * 8), 16, 0, 0);
        __builtin_amdgcn_global_load_lds(
            (const __attribute__((address_space(1))) uint32_t*)(const void*)b0,
            (__attribute__((address_space(3))) uint32_t*)(void*)(dst + 8192 + t * 8), 16, 0, 0);
        __builtin_amdgcn_global_load_lds(
            (const __attribute__((address_space(1))) uint32_t*)(const void*)(b0 + 16384),
            (__attribute__((address_space(3))) uint32_t*)(void*)(dst + 12288 + t * 8), 16, 0, 0);
    };

    auto compute = [&](int buf) {
        const short* L = &lds[buf][0];
        bf16x8 bfr[4], af[8];
        #pragma unroll
        for (int g = 0; g < 4; ++g)
            bfr[g] = *(const bf16x8*)&L[boff + g * 2048];
        #pragma unroll
        for (int m = 0; m < 8; ++m)
            af[m] = *(const bf16x8*)&L[aoff + m * 512];
        __builtin_amdgcn_s_setprio(1);
        #pragma unroll
        for (int g = 0; g < 4; ++g)
            #pragma unroll
            for (int m = 0; m < 8; ++m)
                acc[m][g] = __builtin_amdgcn_mfma_f32_16x16x32_bf16(af[m], bfr[g], acc[m][g], 0, 0, 0);
        __builtin_amdgcn_s_setprio(0);
    };

    // ---- prologue: 3 phases of DMAs in flight (12 loads) ----
    dma(0, 0);
    dma(1, 1);
    dma(2, 2);

    #pragma unroll 1
    for (int p = 0; p < 14; ++p) {
        // retire own phase-p loads (oldest 4 of 12); leave 2 phases in flight
        asm volatile("s_waitcnt vmcnt(8)" ::: "memory");
        __builtin_amdgcn_s_barrier();              // all waves' phase-p loads done
        if (p <= 12) dma(p + 3, (p + 3) & 3);      // overwrites buf read at p-1
        compute(p & 3);
    }
    // ---- tail: phases 14, 15 ----
    asm volatile("s_waitcnt vmcnt(4)" ::: "memory");
    __builtin_amdgcn_s_barrier();
    compute(2);
    asm volatile("s_waitcnt vmcnt(0)" ::: "memory");
    __builtin_amdgcn_s_barrier();
    compute(3);

    // ---- fused LSTM epilogue (lane-local: all 4 gates in acc[m][0..3]) ----
    const size_t HS = (size_t)NROWS * NUNITS;
    const int u = ut * 64 + q * 16 + lr;
    const float bi = bias[u],       bfg = bias[256 + u];
    const float bc = bias[512 + u], bo  = bias[768 + u];
    const float ppi = pi[u], ppf = pf[u], ppo = po[u];
    #pragma unroll
    for (int m = 0; m < 8; ++m) {
        #pragma unroll
        for (int r = 0; r < 4; ++r) {
            const int row = row0 + rh * 128 + m * 16 + hi * 4 + r;
            const size_t o = (size_t)row * NUNITS + u;
            const float cp = c_prev[o];
            float zi = acc[m][0][r] + bi  + ppi * cp;
            float zf = acc[m][1][r] + bfg + ppf * cp;
            float zc = acc[m][2][r] + bc;
            float zo = acc[m][3][r] + bo  + ppo * cp;
            float ig = 1.f / (1.f + __expf(-zi));
            float fg = 1.f / (1.f + __expf(-zf));
            float og = 1.f / (1.f + __expf(-zo));
            zc = fminf(fmaxf(zc, -30.f), 30.f);
            float e2 = __expf(2.f * zc);
            float chat = (e2 - 1.f) / (e2 + 1.f);
            float c  = fg * cp + ig * chat;
            float ccl = fminf(fmaxf(c, -30.f), 30.f);
            float e3 = __expf(2.f * ccl);
            float th = (e3 - 1.f) / (e3 + 1.f);
            float h  = og * th;
            out[o]          = h;
            out[HS + o]     = h;
            out[2 * HS + o] = c;
        }
    }
}

extern "C" void kernel_launch(void* const* d_in, const int* in_sizes, int n_in,
                              void* d_out, int out_size, void* d_ws, size_t ws_size,
                              hipStream_t stream) {
    const float* x  = (const float*)d_in[0];
    const float* h  = (const float*)d_in[1];
    const float* c  = (const float*)d_in[2];
    const float* W  = (const float*)d_in[3];
    const float* b  = (const float*)d_in[4];
    const float* pi = (const float*)d_in[5];
    const float* pf = (const float*)d_in[6];
    const float* po = (const float*)d_in[7];
    float* out = (float*)d_out;

    const size_t aws_bytes = (size_t)NROWS * KTOT * 2;   // 134,217,728
    short* Aws = (short*)d_ws;
    short* Wws = (short*)((char*)d_ws + aws_bytes);

    hipLaunchKernelGGL(convert_kernel, dim3(32768 + 2048), dim3(256), 0, stream,
                       x, h, W, Aws, Wws);
    hipLaunchKernelGGL(lstm_main_kernel, dim3(NROWS / BM * 4), dim3(THREADS), 0, stream,
                       c, b, pi, pf, po, Aws, Wws, out);
}

// Round 11
// 307.732 us; speedup vs baseline: 1.0990x; 1.0990x over previous
//
#include <hip/hip_runtime.h>
#include <cstdint>

// Problem constants
#define NROWS   131072
#define NUNITS  256
#define KTOT    512          // INPUT_DIM + UNITS
#define BM      128          // rows per block
#define THREADS 512

typedef float f32x4  __attribute__((ext_vector_type(4)));
typedef short bf16x8 __attribute__((ext_vector_type(8)));

__device__ __forceinline__ short f2bf(float x) {
    unsigned u = __float_as_uint(x);
    u += 0x7FFFu + ((u >> 16) & 1u);   // round-to-nearest-even
    return (short)(u >> 16);
}

// W [512][1024] fp32 -> Wws [16][1024][32] bf16 (B-fragment order, L2-resident).
// Tiny; A is converted in-main now (no 404 MB prepass round-trip).
__global__ void convert_W_kernel(const float* __restrict__ W, short* __restrict__ Wws) {
    int i = blockIdx.x * 256 + threadIdx.x;       // 0 .. 524287
    int k = i >> 10;
    int c = i & 1023;
    Wws[((size_t)(k >> 5) << 15) + ((size_t)c << 5) + (k & 31)] = f2bf(W[i]);
}

// Main (R7 loop + in-main A staging): grid 4096 = 1024 row-tiles x 4 u-tiles
// (XCD-swizzled -> the 4 u-tiles sharing a row panel co-locate on one XCD; the
// fp32 A panel is HBM-fetched once, L2-served 3x).
// Block: 128 rows x 64 u x 4 gates. 8 waves = 2 row-halves x 4 col-quarters;
// wave tile 64x64, acc[4][4] (all 4 gates lane-local -> fused epilogue).
// Per phase p: [glbA(p+1) 2x dwordx4 fp32 | dmaB(p+2) 2x gload_lds] ->
// compute(p) (8 ds_read_b128 + 16 MFMA, setprio) -> cvt+ds_write A(p+1) ->
// vmcnt(2) (B(p+2) STAYS in flight, R7 discipline) + lgkmcnt(0) -> s_barrier.
// A LDS layout == R7's verified-conflict-free scheme, applied on the WRITE
// side (per-lane ds_write may swizzle; rule #21 applies only to gload_lds).
__global__ void __launch_bounds__(THREADS, 4)
lstm_main_kernel(const float* __restrict__ x, const float* __restrict__ h_prev,
                 const float* __restrict__ c_prev, const float* __restrict__ bias,
                 const float* __restrict__ pi, const float* __restrict__ pf,
                 const float* __restrict__ po, const short* __restrict__ Wws,
                 float* __restrict__ out) {
    __shared__ short Ab[2][4096];   // 2 x 8 KB  bf16 A tiles [128r][32k] swizzled
    __shared__ short Bb[3][8192];   // 3 x 16 KB bf16 B tiles

    const int bid = blockIdx.x;
    const int swz = (bid & 7) * 512 + (bid >> 3);
    const int ut  = swz & 3;
    const int rt  = swz >> 2;
    const int row0 = rt * BM;

    const int t    = threadIdx.x;
    const int lane = t & 63;
    const int w    = t >> 6;
    const int lr   = lane & 15;
    const int hi   = lane >> 4;          // k-granule 0..3
    const int rh   = w >> 2;             // row half 0..1
    const int q    = w & 3;              // col quarter 0..3

    // ---- A staging: thread t -> row t>>2, source granule g = t&3 (8 fp32) ----
    const int arow = t >> 2, ag = t & 3;
    const int avoff = ((row0 + arow) * 256 + ag * 8) * 4;          // bytes into x/h
    const int awr   = arow * 32 + ((ag ^ ((arow >> 1) & 3)) * 8);  // LDS shorts

    // ---- B DMA source byte-offsets (R7 scheme, 0 conflicts measured) ----
    const int u0  = (t >> 2) & 63;
    const int bg0 = t >> 8;              // 0..1
    const int bsw = ((t & 3) ^ ((t >> 3) & 3)) * 8;
    const int bvoff0 = (((bg0    ) * 256 + ut * 64 + u0) * 32 + bsw) * 2;
    const int bvoff1 = (((bg0 + 2) * 256 + ut * 64 + u0) * 32 + bsw) * 2;

    // ---- fragment read offsets (shorts): swizzle matches write side ----
    const int sw   = (hi ^ ((lr >> 1) & 3)) * 8;
    const int aoff = (rh * 64 + lr) * 32 + sw;           // + m*512
    const int boff = (q * 16 + lr) * 32 + sw;            // + g*2048

    f32x4 acc[4][4];
    #pragma unroll
    for (int m = 0; m < 4; ++m)
        #pragma unroll
        for (int g = 0; g < 4; ++g)
            acc[m][g] = (f32x4){0.f, 0.f, 0.f, 0.f};

    f32x4 sreg[2];
    auto glbA = [&](int p) {
        const char* base = (const char*)(p < 8 ? x : h_prev) + ((p & 7) << 7);
        sreg[0] = *(const f32x4*)(base + avoff);
        sreg[1] = *(const f32x4*)(base + avoff + 16);
    };
    auto writeA = [&](int buf) {
        unsigned u0_, u1_, u2_, u3_;
        asm("v_cvt_pk_bf16_f32 %0, %1, %2" : "=v"(u0_) : "v"(sreg[0][0]), "v"(sreg[0][1]));
        asm("v_cvt_pk_bf16_f32 %0, %1, %2" : "=v"(u1_) : "v"(sreg[0][2]), "v"(sreg[0][3]));
        asm("v_cvt_pk_bf16_f32 %0, %1, %2" : "=v"(u2_) : "v"(sreg[1][0]), "v"(sreg[1][1]));
        asm("v_cvt_pk_bf16_f32 %0, %1, %2" : "=v"(u3_) : "v"(sreg[1][2]), "v"(sreg[1][3]));
        int4 v = make_int4((int)u0_, (int)u1_, (int)u2_, (int)u3_);
        *(int4*)&Ab[buf][awr] = v;
    };
    auto dmaB = [&](int p, int buf) {
        const char* wb = (const char*)Wws + ((size_t)p << 16);
        short* dst = &Bb[buf][0];
        __builtin_amdgcn_global_load_lds(
            (const __attribute__((address_space(1))) uint32_t*)(const void*)(wb + bvoff0),
            (__attribute__((address_space(3))) uint32_t*)(void*)(dst + t * 8), 16, 0, 0);
        __builtin_amdgcn_global_load_lds(
            (const __attribute__((address_space(1))) uint32_t*)(const void*)(wb + bvoff1),
            (__attribute__((address_space(3))) uint32_t*)(void*)(dst + 4096 + t * 8), 16, 0, 0);
    };
    auto compute = [&](int bufA, int bufB) {
        const short* A = &Ab[bufA][0];
        const short* B = &Bb[bufB][0];
        bf16x8 af[4], bfr[4];
        #pragma unroll
        for (int m = 0; m < 4; ++m)
            af[m] = *(const bf16x8*)&A[aoff + m * 512];
        #pragma unroll
        for (int g = 0; g < 4; ++g)
            bfr[g] = *(const bf16x8*)&B[boff + g * 2048];
        __builtin_amdgcn_s_setprio(1);
        #pragma unroll
        for (int g = 0; g < 4; ++g)
            #pragma unroll
            for (int m = 0; m < 4; ++m)
                acc[m][g] = __builtin_amdgcn_mfma_f32_16x16x32_bf16(af[m], bfr[g], acc[m][g], 0, 0, 0);
        __builtin_amdgcn_s_setprio(0);
    };

    // ---- prologue: A(0) -> LDS; B(0), B(1) in flight ----
    glbA(0);
    dmaB(0, 0);
    dmaB(1, 1);
    writeA(0);                               // compiler waits A(0) regs (vmcnt(4))
    asm volatile("s_waitcnt vmcnt(2) lgkmcnt(0)" ::: "memory");   // B(0) done, B(1) in flight
    __builtin_amdgcn_s_barrier();

    #pragma unroll 2
    for (int p = 0; p < 16; ++p) {
        const int ca = p & 1, na = ca ^ 1;
        if (p < 15) glbA(p + 1);
        if (p < 14) dmaB(p + 2, (p + 2) % 3);
        compute(ca, p % 3);
        if (p < 15) {
            writeA(na);                       // auto-wait retires A(p+1) (+B(p+1))
            if (p < 14) { asm volatile("s_waitcnt vmcnt(2) lgkmcnt(0)" ::: "memory"); }
            else        { asm volatile("s_waitcnt vmcnt(0) lgkmcnt(0)" ::: "memory"); }
            __builtin_amdgcn_s_barrier();
        }
    }

    // ---- fused LSTM epilogue (lane-local: all 4 gates in acc[m][0..3]) ----
    const size_t HS = (size_t)NROWS * NUNITS;
    const int u = ut * 64 + q * 16 + lr;
    const float bi = bias[u],       bfg = bias[256 + u];
    const float bc = bias[512 + u], bo  = bias[768 + u];
    const float ppi = pi[u], ppf = pf[u], ppo = po[u];
    #pragma unroll
    for (int m = 0; m < 4; ++m) {
        #pragma unroll
        for (int r = 0; r < 4; ++r) {
            const int row = row0 + rh * 64 + m * 16 + hi * 4 + r;
            const size_t o = (size_t)row * NUNITS + u;
            const float cp = c_prev[o];
            float zi = acc[m][0][r] + bi  + ppi * cp;
            float zf = acc[m][1][r] + bfg + ppf * cp;
            float zc = acc[m][2][r] + bc;
            float zo = acc[m][3][r] + bo  + ppo * cp;
            float ig = 1.f / (1.f + __expf(-zi));
            float fg = 1.f / (1.f + __expf(-zf));
            float og = 1.f / (1.f + __expf(-zo));
            zc = fminf(fmaxf(zc, -30.f), 30.f);
            float e2 = __expf(2.f * zc);
            float chat = (e2 - 1.f) / (e2 + 1.f);
            float c  = fg * cp + ig * chat;
            float ccl = fminf(fmaxf(c, -30.f), 30.f);
            float e3 = __expf(2.f * ccl);
            float th = (e3 - 1.f) / (e3 + 1.f);
            float h  = og * th;
            out[o]          = h;
            out[HS + o]     = h;
            out[2 * HS + o] = c;
        }
    }
}

extern "C" void kernel_launch(void* const* d_in, const int* in_sizes, int n_in,
                              void* d_out, int out_size, void* d_ws, size_t ws_size,
                              hipStream_t stream) {
    const float* x  = (const float*)d_in[0];
    const float* h  = (const float*)d_in[1];
    const float* c  = (const float*)d_in[2];
    const float* W  = (const float*)d_in[3];
    const float* b  = (const float*)d_in[4];
    const float* pi = (const float*)d_in[5];
    const float* pf = (const float*)d_in[6];
    const float* po = (const float*)d_in[7];
    float* out = (float*)d_out;

    short* Wws = (short*)d_ws;            // 1 MiB bf16 copy of W in B-frag order

    hipLaunchKernelGGL(convert_W_kernel, dim3(2048), dim3(256), 0, stream, W, Wws);
    hipLaunchKernelGGL(lstm_main_kernel, dim3(NROWS / BM * 4), dim3(THREADS), 0, stream,
                       x, h, c, b, pi, pf, po, Wws, out);
}

// Round 12
// 302.374 us; speedup vs baseline: 1.1184x; 1.0177x over previous
//
#include <hip/hip_runtime.h>
#include <cstdint>

// Problem constants
#define NROWS   131072
#define NUNITS  256
#define KTOT    512          // INPUT_DIM + UNITS
#define BM      128          // rows per block
#define THREADS 512

typedef float f32x4  __attribute__((ext_vector_type(4)));
typedef short bf16x8 __attribute__((ext_vector_type(8)));

__device__ __forceinline__ short f2bf(float x) {
    unsigned u = __float_as_uint(x);
    u += 0x7FFFu + ((u >> 16) & 1u);   // round-to-nearest-even
    return (short)(u >> 16);
}

// W [512][1024] fp32 -> Wws [16][1024][32] bf16 (B-fragment order, L2-resident).
__global__ void convert_W_kernel(const float* __restrict__ W, short* __restrict__ Wws) {
    int i = blockIdx.x * 256 + threadIdx.x;       // 0 .. 524287
    int k = i >> 10;
    int c = i & 1023;
    Wws[((size_t)(k >> 5) << 15) + ((size_t)c << 5) + (k & 31)] = f2bf(W[i]);
}

// Main: grid 4096 = 1024 row-tiles x 4 u-tiles (XCD-swizzled: the 4 u-tiles of
// a row panel co-locate on one XCD -> fp32 A panel HBM-fetched once, L2-served).
// Block: 128 rows x 64 u x 4 gates. 8 waves = 2 row-halves x 4 col-quarters;
// wave tile 64x64, acc[4][4] (all 4 gates lane-local -> fused epilogue).
// Phase p (fully unrolled, 16 phases of BK=32):
//   dmaB(p+1) [2 gload_lds] -> glbA(p+2) [2 dwordx4 fp32] ->
//   writeA(p+1) [auto vmcnt<=4 for sreg(p+1); 4 cvt_pk + ds_write_b128;
//                BEFORE compute -> off the critical tail] ->
//   compute(p) [8 ds_read_b128 + 16 MFMA, setprio] ->
//   s_waitcnt vmcnt(2) lgkmcnt(0)  [retire B(p+1); glbA(p+2) STAYS in flight]
//   s_barrier
// LDS 48KB (A 2x8K + B 2x16K) -> 3 blocks/CU (24 waves) for convoy decorrelation.
// Layouts: R7/R11-verified conflict-free (64B row stride, granule XOR (row>>1)&3;
// B swizzle on gload_lds SOURCE (rule #21), A swizzle on the per-lane ds_write).
__global__ void __launch_bounds__(THREADS, 4)
lstm_main_kernel(const float* __restrict__ x, const float* __restrict__ h_prev,
                 const float* __restrict__ c_prev, const float* __restrict__ bias,
                 const float* __restrict__ pi, const float* __restrict__ pf,
                 const float* __restrict__ po, const short* __restrict__ Wws,
                 float* __restrict__ out) {
    __shared__ short Ab[2][4096];   // 2 x 8 KB  bf16 A tiles [128r][32k] swizzled
    __shared__ short Bb[2][8192];   // 2 x 16 KB bf16 B tiles

    const int bid = blockIdx.x;
    const int swz = (bid & 7) * 512 + (bid >> 3);
    const int ut  = swz & 3;
    const int rt  = swz >> 2;
    const int row0 = rt * BM;

    const int t    = threadIdx.x;
    const int lane = t & 63;
    const int w    = t >> 6;
    const int lr   = lane & 15;
    const int hi   = lane >> 4;          // k-granule 0..3
    const int rh   = w >> 2;             // row half 0..1
    const int q    = w & 3;              // col quarter 0..3

    // ---- A staging: thread t -> row t>>2, source granule g = t&3 (8 fp32) ----
    const int arow = t >> 2, ag = t & 3;
    const int avoff = ((row0 + arow) * 256 + ag * 8) * 4;          // bytes into x/h
    const int awr   = arow * 32 + ((ag ^ ((arow >> 1) & 3)) * 8);  // LDS shorts

    // ---- B DMA source byte-offsets (R7 scheme, 0 conflicts measured) ----
    const int u0  = (t >> 2) & 63;
    const int bg0 = t >> 8;              // 0..1
    const int bsw = ((t & 3) ^ ((t >> 3) & 3)) * 8;
    const int bvoff0 = (((bg0    ) * 256 + ut * 64 + u0) * 32 + bsw) * 2;
    const int bvoff1 = (((bg0 + 2) * 256 + ut * 64 + u0) * 32 + bsw) * 2;

    // ---- fragment read offsets (shorts): swizzle matches write side ----
    const int sw   = (hi ^ ((lr >> 1) & 3)) * 8;
    const int aoff = (rh * 64 + lr) * 32 + sw;           // + m*512
    const int boff = (q * 16 + lr) * 32 + sw;            // + g*2048

    f32x4 acc[4][4];
    #pragma unroll
    for (int m = 0; m < 4; ++m)
        #pragma unroll
        for (int g = 0; g < 4; ++g)
            acc[m][g] = (f32x4){0.f, 0.f, 0.f, 0.f};

    f32x4 sreg[2][2];                    // two in-flight A register sets (parity)
    auto glbA = [&](int p) {
        const char* base = (const char*)(p < 8 ? x : h_prev) + ((p & 7) << 7);
        sreg[p & 1][0] = *(const f32x4*)(base + avoff);
        sreg[p & 1][1] = *(const f32x4*)(base + avoff + 16);
    };
    auto writeA = [&](int p) {
        const f32x4* s = sreg[p & 1];
        unsigned u0_, u1_, u2_, u3_;
        asm("v_cvt_pk_bf16_f32 %0, %1, %2" : "=v"(u0_) : "v"(s[0][0]), "v"(s[0][1]));
        asm("v_cvt_pk_bf16_f32 %0, %1, %2" : "=v"(u1_) : "v"(s[0][2]), "v"(s[0][3]));
        asm("v_cvt_pk_bf16_f32 %0, %1, %2" : "=v"(u2_) : "v"(s[1][0]), "v"(s[1][1]));
        asm("v_cvt_pk_bf16_f32 %0, %1, %2" : "=v"(u3_) : "v"(s[1][2]), "v"(s[1][3]));
        int4 v = make_int4((int)u0_, (int)u1_, (int)u2_, (int)u3_);
        *(int4*)&Ab[p & 1][awr] = v;
    };
    auto dmaB = [&](int p) {
        const char* wb = (const char*)Wws + ((size_t)p << 16);
        short* dst = &Bb[p & 1][0];
        __builtin_amdgcn_global_load_lds(
            (const __attribute__((address_space(1))) uint32_t*)(const void*)(wb + bvoff0),
            (__attribute__((address_space(3))) uint32_t*)(void*)(dst + t * 8), 16, 0, 0);
        __builtin_amdgcn_global_load_lds(
            (const __attribute__((address_space(1))) uint32_t*)(const void*)(wb + bvoff1),
            (__attribute__((address_space(3))) uint32_t*)(void*)(dst + 4096 + t * 8), 16, 0, 0);
    };
    auto compute = [&](int p) {
        const short* A = &Ab[p & 1][0];
        const short* B = &Bb[p & 1][0];
        bf16x8 af[4], bfr[4];
        #pragma unroll
        for (int m = 0; m < 4; ++m)
            af[m] = *(const bf16x8*)&A[aoff + m * 512];
        #pragma unroll
        for (int g = 0; g < 4; ++g)
            bfr[g] = *(const bf16x8*)&B[boff + g * 2048];
        __builtin_amdgcn_s_setprio(1);
        #pragma unroll
        for (int g = 0; g < 4; ++g)
            #pragma unroll
            for (int m = 0; m < 4; ++m)
                acc[m][g] = __builtin_amdgcn_mfma_f32_16x16x32_bf16(af[m], bfr[g], acc[m][g], 0, 0, 0);
        __builtin_amdgcn_s_setprio(0);
    };

    // ---- prologue: A(0) published; B(0) done; glbA(1) in flight ----
    glbA(0);
    dmaB(0);
    glbA(1);
    writeA(0);                            // auto-wait retires glbA(0)
    asm volatile("s_waitcnt vmcnt(2) lgkmcnt(0)" ::: "memory");  // B(0) done; glbA(1) in flight
    __builtin_amdgcn_s_barrier();

    #pragma unroll
    for (int p = 0; p < 16; ++p) {
        if (p <= 14) dmaB(p + 1);         // B lookahead 1 (L2-resident, cheap)
        if (p <= 13) glbA(p + 2);         // A lookahead 2 (HBM ~900cyc covered)
        if (p <= 14) writeA(p + 1);       // auto vmcnt<=4: B(p+1), glbA(p+2) stay in flight
        compute(p);
        if (p <= 13) {
            asm volatile("s_waitcnt vmcnt(2) lgkmcnt(0)" ::: "memory");  // retire B(p+1)
            __builtin_amdgcn_s_barrier();
        } else if (p == 14) {
            asm volatile("s_waitcnt vmcnt(0) lgkmcnt(0)" ::: "memory");
            __builtin_amdgcn_s_barrier();
        }
    }

    // ---- fused LSTM epilogue (lane-local: all 4 gates in acc[m][0..3]) ----
    const size_t HS = (size_t)NROWS * NUNITS;
    const int u = ut * 64 + q * 16 + lr;
    const float bi = bias[u],       bfg = bias[256 + u];
    const float bc = bias[512 + u], bo  = bias[768 + u];
    const float ppi = pi[u], ppf = pf[u], ppo = po[u];
    #pragma unroll
    for (int m = 0; m < 4; ++m) {
        #pragma unroll
        for (int r = 0; r < 4; ++r) {
            const int row = row0 + rh * 64 + m * 16 + hi * 4 + r;
            const size_t o = (size_t)row * NUNITS + u;
            const float cp = c_prev[o];
            float zi = acc[m][0][r] + bi  + ppi * cp;
            float zf = acc[m][1][r] + bfg + ppf * cp;
            float zc = acc[m][2][r] + bc;
            float zo = acc[m][3][r] + bo  + ppo * cp;
            float ig = 1.f / (1.f + __expf(-zi));
            float fg = 1.f / (1.f + __expf(-zf));
            float og = 1.f / (1.f + __expf(-zo));
            zc = fminf(fmaxf(zc, -30.f), 30.f);
            float e2 = __expf(2.f * zc);
            float chat = (e2 - 1.f) / (e2 + 1.f);
            float c  = fg * cp + ig * chat;
            float ccl = fminf(fmaxf(c, -30.f), 30.f);
            float e3 = __expf(2.f * ccl);
            float th = (e3 - 1.f) / (e3 + 1.f);
            float h  = og * th;
            out[o]          = h;
            out[HS + o]     = h;
            out[2 * HS + o] = c;
        }
    }
}

extern "C" void kernel_launch(void* const* d_in, const int* in_sizes, int n_in,
                              void* d_out, int out_size, void* d_ws, size_t ws_size,
                              hipStream_t stream) {
    const float* x  = (const float*)d_in[0];
    const float* h  = (const float*)d_in[1];
    const float* c  = (const float*)d_in[2];
    const float* W  = (const float*)d_in[3];
    const float* b  = (const float*)d_in[4];
    const float* pi = (const float*)d_in[5];
    const float* pf = (const float*)d_in[6];
    const float* po = (const float*)d_in[7];
    float* out = (float*)d_out;

    short* Wws = (short*)d_ws;            // 1 MiB bf16 copy of W in B-frag order

    hipLaunchKernelGGL(convert_W_kernel, dim3(2048), dim3(256), 0, stream, W, Wws);
    hipLaunchKernelGGL(lstm_main_kernel, dim3(NROWS / BM * 4), dim3(THREADS), 0, stream,
                       x, h, c, b, pi, pf, po, Wws, out);
}